// Round 1
// baseline (1193.885 us; speedup 1.0000x reference)
//
#include <hip/hip_runtime.h>
#include <math.h>

#define B_ 1024
#define C_ 64
#define D_ 256
#define N_ 512

#define TOPK_MARGIN 1e-3f
#define MAXBAND 24

// ---------------------------------------------------------------------------
// Kernel 1: drive[b,c,n] = sum_d x_in[b,d]*W_ff[c,d,n]
//                        + 0.3*sum_d x_ctx[b,d]*W_ctx[c,d,n] + bias[c,n]
// f32 vector GEMM over concatenated K=512 (x_ctx pre-scaled by 0.3).
// Tile 128(M) x 128(N), K-chunk 32, 256 threads, 8x8 accumulators/thread.
// Writes drive into the activation output region (overwritten in-place by K2).
// ---------------------------------------------------------------------------
__global__ __launch_bounds__(256)
void k_drive(const float* __restrict__ x_in, const float* __restrict__ x_ctx,
             const float* __restrict__ W_ff, const float* __restrict__ W_ctx,
             const float* __restrict__ bias, float* __restrict__ drive)
{
    __shared__ float Xs[32][132];   // [k][m], row = 528B (16B-aligned)
    __shared__ float Ws[32][132];   // [k][n]
    const int c  = blockIdx.z;
    const int m0 = blockIdx.y * 128;
    const int n0 = blockIdx.x * 128;
    const int tid = threadIdx.x;
    const int tx = tid & 15;        // n-dim (8 cols each)
    const int ty = tid >> 4;        // m-dim (8 rows each)

    float acc[8][8];
#pragma unroll
    for (int i = 0; i < 8; ++i)
#pragma unroll
        for (int j = 0; j < 8; ++j) acc[i][j] = 0.f;

    const size_t wbase = (size_t)c * D_ * N_;

    for (int kb = 0; kb < 512; kb += 32) {
        // X tile: 128 rows x 32 k, float4 along k (coalesced)
#pragma unroll
        for (int i = 0; i < 4; ++i) {
            int idx = tid + i * 256;       // 0..1023
            int row = idx >> 3;            // 0..127
            int kf4 = idx & 7;             // 0..7
            float4 v;
            if (kb < 256) {
                v = *(const float4*)(x_in + (size_t)(m0 + row) * D_ + kb + kf4 * 4);
            } else {
                v = *(const float4*)(x_ctx + (size_t)(m0 + row) * D_ + (kb - 256) + kf4 * 4);
                v.x *= 0.3f; v.y *= 0.3f; v.z *= 0.3f; v.w *= 0.3f;
            }
            Xs[kf4 * 4 + 0][row] = v.x;
            Xs[kf4 * 4 + 1][row] = v.y;
            Xs[kf4 * 4 + 2][row] = v.z;
            Xs[kf4 * 4 + 3][row] = v.w;
        }
        // W tile: 32 k x 128 n, float4 along n (coalesced)
#pragma unroll
        for (int i = 0; i < 4; ++i) {
            int idx = tid + i * 256;
            int kk  = idx >> 5;            // 0..31
            int nf4 = idx & 31;            // 0..31
            const float* src = (kb < 256)
                ? (W_ff  + wbase + (size_t)(kb + kk) * N_ + n0 + nf4 * 4)
                : (W_ctx + wbase + (size_t)(kb - 256 + kk) * N_ + n0 + nf4 * 4);
            *(float4*)&Ws[kk][nf4 * 4] = *(const float4*)src;
        }
        __syncthreads();
#pragma unroll
        for (int kk = 0; kk < 32; ++kk) {
            float xr[8], wr[8];
            *(float4*)&xr[0] = *(const float4*)&Xs[kk][ty * 8];
            *(float4*)&xr[4] = *(const float4*)&Xs[kk][ty * 8 + 4];
            *(float4*)&wr[0] = *(const float4*)&Ws[kk][tx * 8];
            *(float4*)&wr[4] = *(const float4*)&Ws[kk][tx * 8 + 4];
#pragma unroll
            for (int i = 0; i < 8; ++i)
#pragma unroll
                for (int j = 0; j < 8; ++j)
                    acc[i][j] = fmaf(xr[i], wr[j], acc[i][j]);
        }
        __syncthreads();
    }
    // epilogue: + bias, store
    float bv[8];
    *(float4*)&bv[0] = *(const float4*)(bias + (size_t)c * N_ + n0 + tx * 8);
    *(float4*)&bv[4] = *(const float4*)(bias + (size_t)c * N_ + n0 + tx * 8 + 4);
#pragma unroll
    for (int i = 0; i < 8; ++i) {
        int b = m0 + ty * 8 + i;
        float o[8];
#pragma unroll
        for (int j = 0; j < 8; ++j) o[j] = acc[i][j] + bv[j];
        float* dst = drive + ((size_t)b * C_ + c) * N_ + n0 + tx * 8;
        *(float4*)dst       = *(float4*)&o[0];
        *(float4*)(dst + 4) = *(float4*)&o[4];
    }
}

// ---------------------------------------------------------------------------
// Wave helpers
// ---------------------------------------------------------------------------
__device__ __forceinline__ float wredmaxf(float v) {
#pragma unroll
    for (int o = 32; o; o >>= 1) v = fmaxf(v, __shfl_xor(v, o));
    return v;
}
__device__ __forceinline__ float wredsumf(float v) {
#pragma unroll
    for (int o = 32; o; o >>= 1) v += __shfl_xor(v, o);
    return v;
}
__device__ __forceinline__ int wredsumi(int v) {
#pragma unroll
    for (int o = 32; o; o >>= 1) v += __shfl_xor(v, o);
    return v;
}
__device__ __forceinline__ double wredsumd(double v) {
#pragma unroll
    for (int o = 32; o; o >>= 1) v += __shfl_xor(v, o);
    return v;
}

// ---------------------------------------------------------------------------
// Kernel 2: per-(b,c)-row top-k mask + normalize, in place over drive.
// One wave (64 lanes) per row; 8 elements per lane.
// Exact kth-largest by iterative extraction; near-tie band (|boosted - t|
// <= 1e-3) resolved by f64 recomputation replicating reference op order.
// ---------------------------------------------------------------------------
__global__ __launch_bounds__(256)
void k_topk(const float* __restrict__ x_in, const float* __restrict__ x_ctx,
            const float* __restrict__ W_ff, const float* __restrict__ W_ctx,
            const float* __restrict__ bias, const float* __restrict__ avg_act,
            const int* __restrict__ kptr, float* __restrict__ act)
{
    const int wave = threadIdx.x >> 6;
    const int lane = threadIdx.x & 63;
    const int row  = blockIdx.x * 4 + wave;   // row = b*C + c
    const int b    = row >> 6;
    const int c    = row & 63;
    const int kv   = *kptr;

    float* arow = act + (size_t)row * N_;
    const float* avgrow  = avg_act + (size_t)c * N_;
    const float* biasrow = bias    + (size_t)c * N_;

    float drv[8], boo[8];
#pragma unroll
    for (int j = 0; j < 8; ++j) {
        int n = lane + (j << 6);
        drv[j] = arow[n];
        float boost = log1pf(0.05f / (avgrow[n] + 1e-6f));  // * (0.01*100) == 1.0
        boo[j] = drv[j] + boost;
    }

    // ---- exact top-kv threshold by iterative extraction ----
    unsigned exm = 0;
    float t = 0.f;
    for (int it = 0; it < kv; ++it) {
        float lm = -INFINITY; int li = -1;
#pragma unroll
        for (int j = 0; j < 8; ++j)
            if (!((exm >> j) & 1u) && boo[j] > lm) { lm = boo[j]; li = j; }
        float wm = wredmaxf(lm);
        unsigned long long bal = __ballot(lm == wm);
        int lowest = (int)__builtin_ctzll(bal);
        if (lane == lowest) exm |= (1u << li);
        t = wm;
    }

    // ---- band analysis ----
    bool inband[8];
    int cb_l = 0, cs_l = 0;
#pragma unroll
    for (int j = 0; j < 8; ++j) {
        inband[j] = fabsf(boo[j] - t) <= TOPK_MARGIN;
        cb_l += inband[j] ? 1 : 0;
        cs_l += (boo[j] > t + TOPK_MARGIN) ? 1 : 0;
    }
    int cb = wredsumi(cb_l);
    int cs = wredsumi(cs_l);

    bool sel[8];
    if (cb <= 1) {
        // no near-ties: f32 decision is provably the f64 decision
#pragma unroll
        for (int j = 0; j < 8; ++j) sel[j] = (boo[j] >= t);
    } else {
        // ---- f64 fixup of the contested band ----
        double bandv[MAXBAND];
        int    bandn[MAXBAND];
        int nb = 0;
        const float* xi = x_in  + (size_t)b * D_;
        const float* xc = x_ctx + (size_t)b * D_;
        const size_t wb = (size_t)c * D_ * N_;
        for (int j = 0; j < 8; ++j) {
            unsigned long long bm = __ballot(inband[j]);
            while (bm && nb < MAXBAND) {
                int L = (int)__builtin_ctzll(bm); bm &= bm - 1;
                int n = L + (j << 6);
                const float* wffcol = W_ff  + wb + n;
                const float* wctcol = W_ctx + wb + n;
                double sff = 0.0, sct = 0.0;
#pragma unroll
                for (int dd = 0; dd < 4; ++dd) {
                    int d = lane + (dd << 6);
                    sff += (double)xi[d] * (double)wffcol[(size_t)d * N_];
                    sct += (double)xc[d] * (double)wctcol[(size_t)d * N_];
                }
                sff = wredsumd(sff);
                sct = wredsumd(sct);
                double d64 = sff + sct * 0.3 + (double)biasrow[n];
                double b64 = d64 + log1p(0.05 / ((double)avgrow[n] + 1e-6));
                bandv[nb] = b64; bandn[nb] = n; ++nb;
            }
        }
        int need = kv - cs;
        if (need < 1) need = 1;
        if (need > nb) need = nb;
        unsigned used = 0; double thr64 = 0.0;
        for (int it = 0; it < need; ++it) {
            double bm2 = -1e300; int bi = 0;
            for (int q = 0; q < nb; ++q)
                if (!((used >> q) & 1u) && bandv[q] > bm2) { bm2 = bandv[q]; bi = q; }
            used |= (1u << bi);
            thr64 = bm2;
        }
#pragma unroll
        for (int j = 0; j < 8; ++j) {
            if (!inband[j]) {
                sel[j] = (boo[j] >= t);    // safe: > t+M selected, < t-M excluded
            } else {
                int n = lane + (j << 6);
                double v = -1e300;
                for (int q = 0; q < nb; ++q) if (bandn[q] == n) v = bandv[q];
                sel[j] = (v >= thr64);
            }
        }
    }

    // ---- relu * mask, normalize to sum k, store ----
    float a[8]; float s_l = 0.f;
#pragma unroll
    for (int j = 0; j < 8; ++j) {
        a[j] = sel[j] ? fmaxf(drv[j], 0.f) : 0.f;
        s_l += a[j];
    }
    float s = wredsumf(s_l);
    float den = s + 1e-8f;
    float kf = (float)kv;
#pragma unroll
    for (int j = 0; j < 8; ++j) {
        int n = lane + (j << 6);
        arow[n] = a[j] / den * kf;
    }
}

// ---------------------------------------------------------------------------
// Kernel 3: predictions[b,c,:] = sum_{n: act>0} act[b,c,n] * W_pred[c,n,:]
//           errors = x_in[b,:] - predictions
// One block (256 threads = D) per (b,c); c-major grid for W_pred locality.
// ---------------------------------------------------------------------------
__global__ __launch_bounds__(256)
void k_pred(const float* __restrict__ act, const float* __restrict__ W_pred,
            const float* __restrict__ x_in,
            float* __restrict__ pred, float* __restrict__ err)
{
    const int c = blockIdx.x >> 10;     // / B_
    const int b = blockIdx.x & 1023;
    __shared__ float sval[64];
    __shared__ int   sidx[64];
    __shared__ int   scnt;
    if (threadIdx.x == 0) scnt = 0;
    __syncthreads();
    const float* arow = act + ((size_t)b * C_ + c) * N_;
    for (int n = threadIdx.x; n < N_; n += 256) {
        float v = arow[n];
        if (v != 0.f) {
            int p = atomicAdd(&scnt, 1);
            if (p < 64) { sval[p] = v; sidx[p] = n; }
        }
    }
    __syncthreads();
    int cnt = scnt < 64 ? scnt : 64;
    const int d = threadIdx.x;
    const float* wp = W_pred + (size_t)c * N_ * D_;
    float p = 0.f;
    for (int q = 0; q < cnt; ++q)
        p = fmaf(sval[q], wp[(size_t)sidx[q] * D_ + d], p);
    size_t o = ((size_t)b * C_ + c) * D_ + d;
    pred[o] = p;
    err[o]  = x_in[(size_t)b * D_ + d] - p;
}

// ---------------------------------------------------------------------------
extern "C" void kernel_launch(void* const* d_in, const int* in_sizes, int n_in,
                              void* d_out, int out_size, void* d_ws, size_t ws_size,
                              hipStream_t stream)
{
    const float* x_in   = (const float*)d_in[0];
    const float* x_ctx  = (const float*)d_in[1];
    const float* W_ff   = (const float*)d_in[2];
    const float* W_ctx  = (const float*)d_in[3];
    const float* W_pred = (const float*)d_in[4];
    const float* bias   = (const float*)d_in[5];
    const float* avg    = (const float*)d_in[6];
    const int*   kptr   = (const int*)d_in[7];

    float* act  = (float*)d_out;                        // [B,C,N]
    float* pred = act  + (size_t)B_ * C_ * N_;          // [B,C,D]
    float* err  = pred + (size_t)B_ * C_ * D_;          // [B,C,D]

    dim3 g1(N_ / 128, B_ / 128, C_);                    // (4, 8, 64)
    k_drive<<<g1, 256, 0, stream>>>(x_in, x_ctx, W_ff, W_ctx, bias, act);
    k_topk<<<(B_ * C_) / 4, 256, 0, stream>>>(x_in, x_ctx, W_ff, W_ctx,
                                              bias, avg, kptr, act);
    k_pred<<<B_ * C_, 256, 0, stream>>>(act, W_pred, x_in, pred, err);
}

// Round 2
// 850.429 us; speedup vs baseline: 1.4039x; 1.4039x over previous
//
#include <hip/hip_runtime.h>
#include <math.h>

#define B_ 1024
#define C_ 64
#define D_ 256
#define N_ 512

#define TOPK_MARGIN 1e-3f

typedef __attribute__((ext_vector_type(8))) short short8;
typedef __attribute__((ext_vector_type(4))) float f32x4;

// ---------------------------------------------------------------------------
// helpers
// ---------------------------------------------------------------------------
__device__ __forceinline__ float wredmaxf(float v) {
#pragma unroll
    for (int o = 32; o; o >>= 1) v = fmaxf(v, __shfl_xor(v, o));
    return v;
}
__device__ __forceinline__ float wredsumf(float v) {
#pragma unroll
    for (int o = 32; o; o >>= 1) v += __shfl_xor(v, o);
    return v;
}
__device__ __forceinline__ int wredsumi(int v) {
#pragma unroll
    for (int o = 32; o; o >>= 1) v += __shfl_xor(v, o);
    return v;
}
__device__ __forceinline__ double wredsumd(double v) {
#pragma unroll
    for (int o = 32; o; o >>= 1) v += __shfl_xor(v, o);
    return v;
}
__device__ __forceinline__ double wredmaxd(double v) {
#pragma unroll
    for (int o = 32; o; o >>= 1) { double t = __shfl_xor(v, o); v = (t > v) ? t : v; }
    return v;
}

// split f32 -> bf16 hi + bf16 lo (truncation; residual ~2^-17 relative)
__device__ __forceinline__ void split8(const float* v, short8* hi, short8* lo) {
    short8 h, l;
#pragma unroll
    for (int q = 0; q < 8; ++q) {
        unsigned u = __float_as_uint(v[q]);
        float hf = __uint_as_float(u & 0xFFFF0000u);
        float lf = v[q] - hf;
        h[q] = (short)(u >> 16);
        l[q] = (short)(__float_as_uint(lf) >> 16);
    }
    *hi = h; *lo = l;
}

__device__ __forceinline__ void gload_lds16(const void* g, void* l) {
    __builtin_amdgcn_global_load_lds(
        (const __attribute__((address_space(1))) void*)g,
        (__attribute__((address_space(3))) void*)l, 16, 0, 0);
}

// ---------------------------------------------------------------------------
// P1: split X = [x_in | 0.3*x_ctx]  (B x 512 f32) into bf16 hi/lo,
// layout Ahi[kb][b][k'] (kb = k/64, k' = k%64), k-contiguous.
// ---------------------------------------------------------------------------
__global__ __launch_bounds__(256)
void k_split_x(const float* __restrict__ x_in, const float* __restrict__ x_ctx,
               short* __restrict__ Ahi, short* __restrict__ Alo)
{
    int gid = blockIdx.x * 256 + threadIdx.x;       // 65536 = 1024 rows * 64
    int b = gid >> 6, tn = gid & 63, k0 = tn * 8;
    float v[8];
    if (k0 < 256) {
        *(float4*)&v[0] = *(const float4*)(x_in + (size_t)b * 256 + k0);
        *(float4*)&v[4] = *(const float4*)(x_in + (size_t)b * 256 + k0 + 4);
    } else {
        *(float4*)&v[0] = *(const float4*)(x_ctx + (size_t)b * 256 + k0 - 256);
        *(float4*)&v[4] = *(const float4*)(x_ctx + (size_t)b * 256 + k0 - 252);
#pragma unroll
        for (int q = 0; q < 8; ++q) v[q] *= 0.3f;
    }
    short8 h, l; split8(v, &h, &l);
    size_t off = ((size_t)(k0 >> 6) * 1024 + b) * 64 + (k0 & 63);
    *(short8*)(Ahi + off) = h;
    *(short8*)(Alo + off) = l;
}

// ---------------------------------------------------------------------------
// P2: split Wcat[c][k][n] (k<256 -> W_ff, else W_ctx) into bf16 hi/lo,
// layout Whi[c][nb(4)][kb(8)][n'(128)][k'(64)]  (16KB tiles, k-contiguous).
// ---------------------------------------------------------------------------
__global__ __launch_bounds__(256)
void k_split_w(const float* __restrict__ W_ff, const float* __restrict__ W_ctx,
               short* __restrict__ Whi, short* __restrict__ Wlo)
{
    int blk = blockIdx.x;                            // 8192 = 64c * 128
    int c = blk >> 7;
    int t = (blk & 127) * 256 + threadIdx.x;         // 0..32767 = 64kg * 512n
    int kg = t >> 9, n = t & 511, k0 = kg * 8;
    const float* src = (k0 < 256)
        ? (W_ff  + ((size_t)c * 256 + k0) * 512 + n)
        : (W_ctx + ((size_t)c * 256 + (k0 - 256)) * 512 + n);
    float v[8];
#pragma unroll
    for (int q = 0; q < 8; ++q) v[q] = src[(size_t)q * 512];
    short8 h, l; split8(v, &h, &l);
    size_t off = ((((size_t)c * 4 + (n >> 7)) * 8 + (k0 >> 6)) * 128 + (n & 127)) * 64
               + (k0 & 63);
    *(short8*)(Whi + off) = h;
    *(short8*)(Wlo + off) = l;
}

// ---------------------------------------------------------------------------
// P3: boost table  boost[c][n] = log1pf(0.05/(avg+1e-6))
// ---------------------------------------------------------------------------
__global__ __launch_bounds__(256)
void k_boost(const float* __restrict__ avg, float* __restrict__ boost)
{
    int i = blockIdx.x * 256 + threadIdx.x;          // 32768
    boost[i] = log1pf(0.05f / (avg[i] + 1e-6f));
}

// ---------------------------------------------------------------------------
// G: drive GEMM via MFMA 16x16x32 bf16, 3-product split.
// 128x128 tile, BK=64, 4 waves (2x2, each 64x64), m97-style 2-barrier loop,
// global_load_lds width 16, linear LDS.
// ---------------------------------------------------------------------------
__global__ __launch_bounds__(256)
void k_drive_mfma(const short* __restrict__ Ahi, const short* __restrict__ Alo,
                  const short* __restrict__ Whi, const short* __restrict__ Wlo,
                  const float* __restrict__ bias, float* __restrict__ drive)
{
    __shared__ short lds[32768];                     // 4 x 16KB tiles
    const int nb = blockIdx.x, mb = blockIdx.y, c = blockIdx.z;
    const int tid = threadIdx.x, lane = tid & 63, wid = tid >> 6;
    const int wm = wid >> 1, wn = wid & 1;
    const int m0 = mb * 128, n0 = nb * 128;

    f32x4 acc[4][4];
#pragma unroll
    for (int i = 0; i < 4; ++i)
#pragma unroll
        for (int j = 0; j < 4; ++j) acc[i][j] = (f32x4){0.f, 0.f, 0.f, 0.f};

    // per-wave staging assignment: wave w stages tile w
    const short* gbase;
    size_t kstep;
    if (wid == 0)      { gbase = Ahi + (size_t)m0 * 64;                  kstep = 65536; }
    else if (wid == 1) { gbase = Alo + (size_t)m0 * 64;                  kstep = 65536; }
    else if (wid == 2) { gbase = Whi + ((size_t)(c * 4 + nb) * 8) * 8192; kstep = 8192; }
    else               { gbase = Wlo + ((size_t)(c * 4 + nb) * 8) * 8192; kstep = 8192; }
    short* lbase = lds + wid * 8192;

    for (int kb = 0; kb < 8; ++kb) {
        const short* g = gbase + (size_t)kb * kstep + lane * 8;   // lane*16B
#pragma unroll
        for (int i = 0; i < 16; ++i)
            gload_lds16(g + i * 512, lbase + i * 512);
        __syncthreads();                 // compiler drains vmcnt before barrier

        const int rA = lane & 15;
#pragma unroll
        for (int s = 0; s < 2; ++s) {
            const int ko = s * 32 + (lane >> 4) * 8;
            short8 ah[4], al[4], bh[4], bl[4];
#pragma unroll
            for (int i = 0; i < 4; ++i) {
                int offA = (wm * 64 + i * 16 + rA) * 64 + ko;
                ah[i] = *(const short8*)(lds + offA);
                al[i] = *(const short8*)(lds + 8192 + offA);
                int offB = (wn * 64 + i * 16 + rA) * 64 + ko;
                bh[i] = *(const short8*)(lds + 16384 + offB);
                bl[i] = *(const short8*)(lds + 24576 + offB);
            }
#pragma unroll
            for (int i = 0; i < 4; ++i)
#pragma unroll
                for (int j = 0; j < 4; ++j) {
                    acc[i][j] = __builtin_amdgcn_mfma_f32_16x16x32_bf16(ah[i], bh[j], acc[i][j], 0, 0, 0);
                    acc[i][j] = __builtin_amdgcn_mfma_f32_16x16x32_bf16(ah[i], bl[j], acc[i][j], 0, 0, 0);
                    acc[i][j] = __builtin_amdgcn_mfma_f32_16x16x32_bf16(al[i], bh[j], acc[i][j], 0, 0, 0);
                }
        }
        __syncthreads();
    }

    // epilogue: + bias, store. C/D layout: col=lane&15, row=(lane>>4)*4+reg
    const int col = lane & 15, rq = (lane >> 4) * 4;
#pragma unroll
    for (int j = 0; j < 4; ++j) {
        float bv = bias[(size_t)c * 512 + n0 + wn * 64 + j * 16 + col];
#pragma unroll
        for (int i = 0; i < 4; ++i) {
#pragma unroll
            for (int r = 0; r < 4; ++r) {
                int bi = m0 + wm * 64 + i * 16 + rq + r;
                drive[((size_t)bi * 64 + c) * 512 + n0 + wn * 64 + j * 16 + col]
                    = acc[i][j][r] + bv;
            }
        }
    }
}

// ---------------------------------------------------------------------------
// Fallback f32 drive GEMM (round-1 kernel, used only if ws too small)
// ---------------------------------------------------------------------------
__global__ __launch_bounds__(256)
void k_drive(const float* __restrict__ x_in, const float* __restrict__ x_ctx,
             const float* __restrict__ W_ff, const float* __restrict__ W_ctx,
             const float* __restrict__ bias, float* __restrict__ drive)
{
    __shared__ float Xs[32][132];
    __shared__ float Ws[32][132];
    const int c  = blockIdx.z;
    const int m0 = blockIdx.y * 128;
    const int n0 = blockIdx.x * 128;
    const int tid = threadIdx.x;
    const int tx = tid & 15;
    const int ty = tid >> 4;

    float acc[8][8];
#pragma unroll
    for (int i = 0; i < 8; ++i)
#pragma unroll
        for (int j = 0; j < 8; ++j) acc[i][j] = 0.f;

    const size_t wbase = (size_t)c * D_ * N_;

    for (int kb = 0; kb < 512; kb += 32) {
#pragma unroll
        for (int i = 0; i < 4; ++i) {
            int idx = tid + i * 256;
            int row = idx >> 3;
            int kf4 = idx & 7;
            float4 v;
            if (kb < 256) {
                v = *(const float4*)(x_in + (size_t)(m0 + row) * D_ + kb + kf4 * 4);
            } else {
                v = *(const float4*)(x_ctx + (size_t)(m0 + row) * D_ + (kb - 256) + kf4 * 4);
                v.x *= 0.3f; v.y *= 0.3f; v.z *= 0.3f; v.w *= 0.3f;
            }
            Xs[kf4 * 4 + 0][row] = v.x;
            Xs[kf4 * 4 + 1][row] = v.y;
            Xs[kf4 * 4 + 2][row] = v.z;
            Xs[kf4 * 4 + 3][row] = v.w;
        }
#pragma unroll
        for (int i = 0; i < 4; ++i) {
            int idx = tid + i * 256;
            int kk  = idx >> 5;
            int nf4 = idx & 31;
            const float* src = (kb < 256)
                ? (W_ff  + wbase + (size_t)(kb + kk) * N_ + n0 + nf4 * 4)
                : (W_ctx + wbase + (size_t)(kb - 256 + kk) * N_ + n0 + nf4 * 4);
            *(float4*)&Ws[kk][nf4 * 4] = *(const float4*)src;
        }
        __syncthreads();
#pragma unroll
        for (int kk = 0; kk < 32; ++kk) {
            float xr[8], wr[8];
            *(float4*)&xr[0] = *(const float4*)&Xs[kk][ty * 8];
            *(float4*)&xr[4] = *(const float4*)&Xs[kk][ty * 8 + 4];
            *(float4*)&wr[0] = *(const float4*)&Ws[kk][tx * 8];
            *(float4*)&wr[4] = *(const float4*)&Ws[kk][tx * 8 + 4];
#pragma unroll
            for (int i = 0; i < 8; ++i)
#pragma unroll
                for (int j = 0; j < 8; ++j)
                    acc[i][j] = fmaf(xr[i], wr[j], acc[i][j]);
        }
        __syncthreads();
    }
    float bv[8];
    *(float4*)&bv[0] = *(const float4*)(bias + (size_t)c * N_ + n0 + tx * 8);
    *(float4*)&bv[4] = *(const float4*)(bias + (size_t)c * N_ + n0 + tx * 8 + 4);
#pragma unroll
    for (int i = 0; i < 8; ++i) {
        int b = m0 + ty * 8 + i;
        float o[8];
#pragma unroll
        for (int j = 0; j < 8; ++j) o[j] = acc[i][j] + bv[j];
        float* dst = drive + ((size_t)b * C_ + c) * N_ + n0 + tx * 8;
        *(float4*)dst       = *(float4*)&o[0];
        *(float4*)(dst + 4) = *(float4*)&o[4];
    }
}

// ---------------------------------------------------------------------------
// k_select: fused top-k mask + normalize + predictions + errors.
// One wave per (b,c) row; element j of lane L is n = L*4 + (j&3) + (j>=4)*256.
// f64 band fixup uses lane-distributed scalars (no scratch arrays).
// ---------------------------------------------------------------------------
__global__ __launch_bounds__(256)
void k_select(const float* __restrict__ x_in, const float* __restrict__ x_ctx,
              const float* __restrict__ W_ff, const float* __restrict__ W_ctx,
              const float* __restrict__ W_pred,
              const float* __restrict__ bias, const float* __restrict__ avg_act,
              const float* __restrict__ boost_tab,
              const int* __restrict__ kptr,
              float* __restrict__ act, float* __restrict__ pred,
              float* __restrict__ err)
{
    const int wave = threadIdx.x >> 6, lane = threadIdx.x & 63;
    const int row = blockIdx.x * 4 + wave;          // row = b*C + c
    const int b = row >> 6, c = row & 63;
    const int kv = *kptr;

    float* arow = act + (size_t)row * N_;
    const float* avgrow = avg_act + (size_t)c * N_;

    float drv[8], boo[8];
    {
        float4 d0 = *(const float4*)(arow + lane * 4);
        float4 d1 = *(const float4*)(arow + 256 + lane * 4);
        drv[0] = d0.x; drv[1] = d0.y; drv[2] = d0.z; drv[3] = d0.w;
        drv[4] = d1.x; drv[5] = d1.y; drv[6] = d1.z; drv[7] = d1.w;
    }
    if (boost_tab) {
        float4 t0 = *(const float4*)(boost_tab + (size_t)c * 512 + lane * 4);
        float4 t1 = *(const float4*)(boost_tab + (size_t)c * 512 + 256 + lane * 4);
        boo[0] = drv[0] + t0.x; boo[1] = drv[1] + t0.y;
        boo[2] = drv[2] + t0.z; boo[3] = drv[3] + t0.w;
        boo[4] = drv[4] + t1.x; boo[5] = drv[5] + t1.y;
        boo[6] = drv[6] + t1.z; boo[7] = drv[7] + t1.w;
    } else {
#pragma unroll
        for (int j = 0; j < 8; ++j) {
            int n = lane * 4 + (j & 3) + ((j >= 4) ? 256 : 0);
            boo[j] = drv[j] + log1pf(0.05f / (avgrow[n] + 1e-6f));
        }
    }

    // ---- exact top-kv threshold by iterative extraction (f32) ----
    unsigned exm = 0;
    float t = 0.f;
    for (int it = 0; it < kv; ++it) {
        float lm = -INFINITY; int li = -1;
#pragma unroll
        for (int j = 0; j < 8; ++j)
            if (!((exm >> j) & 1u) && boo[j] > lm) { lm = boo[j]; li = j; }
        float wm = wredmaxf(lm);
        unsigned long long bal = __ballot(lm == wm);
        int lowest = (int)__builtin_ctzll(bal);
        if (lane == lowest) exm |= (1u << li);
        t = wm;
    }

    // ---- band analysis ----
    bool inband[8], sel[8];
    int cb_l = 0, cs_l = 0;
#pragma unroll
    for (int j = 0; j < 8; ++j) {
        inband[j] = fabsf(boo[j] - t) <= TOPK_MARGIN;
        cb_l += inband[j] ? 1 : 0;
        cs_l += (boo[j] > t + TOPK_MARGIN) ? 1 : 0;
        sel[j] = (boo[j] >= t);
    }
    int cb = wredsumi(cb_l);
    int cs = wredsumi(cs_l);

    if (cb > 1) {
        // ---- f64 fixup, band elements distributed one per lane ----
        int nbTot = 0;
        double myv = -1e300; int myn = -1;
        const float* xi = x_in + (size_t)b * 256;
        const float* xc = x_ctx + (size_t)b * 256;
        const size_t wb = (size_t)c * 256 * 512;
        const float* brow = bias + (size_t)c * 512;
        for (int j = 0; j < 8; ++j) {
            unsigned long long bm = __ballot(inband[j]);
            while (bm && nbTot < 64) {
                int L = (int)__builtin_ctzll(bm); bm &= bm - 1;
                int n = L * 4 + (j & 3) + ((j >= 4) ? 256 : 0);
                double sff = 0.0, sct = 0.0;
#pragma unroll
                for (int dd = 0; dd < 4; ++dd) {
                    int d = lane + (dd << 6);
                    sff += (double)xi[d] * (double)W_ff[wb + (size_t)d * 512 + n];
                    sct += (double)xc[d] * (double)W_ctx[wb + (size_t)d * 512 + n];
                }
                sff = wredsumd(sff);
                sct = wredsumd(sct);
                double b64 = sff + sct * 0.3 + (double)brow[n]
                           + log1p(0.05 / ((double)avgrow[n] + 1e-6));
                if (lane == nbTot) { myv = b64; myn = n; }
                ++nbTot;
            }
        }
        int need = kv - cs;
        if (need < 1) need = 1;
        if (need > nbTot) need = nbTot;
        double cur = myv, thr = 0.0;
        for (int it = 0; it < need; ++it) {
            double m = wredmaxd(cur);
            unsigned long long balm = __ballot(cur == m);
            int low = (int)__builtin_ctzll(balm);
            if (lane == low) cur = -1e300;
            thr = m;
        }
        int mysel = (myn >= 0 && myv >= thr) ? 1 : 0;
        for (int q = 0; q < nbTot; ++q) {
            int nq = __shfl(myn, q);
            int sq = __shfl(mysel, q);
            int tl = (nq & 255) >> 2;
            int tj = (nq & 3) + ((nq >= 256) ? 4 : 0);
            if (lane == tl) sel[tj] = (sq != 0);
        }
    }

    // ---- relu * mask, normalize to sum k, store act ----
    float a[8]; float s_l = 0.f;
#pragma unroll
    for (int j = 0; j < 8; ++j) {
        a[j] = sel[j] ? fmaxf(drv[j], 0.f) : 0.f;
        s_l += a[j];
    }
    float s = wredsumf(s_l);
    float scale = (float)kv / (s + 1e-8f);
#pragma unroll
    for (int j = 0; j < 8; ++j) a[j] *= scale;
    {
        float4 o0 = {a[0], a[1], a[2], a[3]};
        float4 o1 = {a[4], a[5], a[6], a[7]};
        *(float4*)(arow + lane * 4) = o0;
        *(float4*)(arow + 256 + lane * 4) = o1;
    }

    // ---- predictions + errors (fused; winners broadcast via ballot) ----
    float4 acc4 = {0.f, 0.f, 0.f, 0.f};
    const float* wp = W_pred + (size_t)c * (N_ * D_);
    for (int j = 0; j < 8; ++j) {
        unsigned long long bm = __ballot(a[j] != 0.f);
        while (bm) {
            int src = (int)__builtin_ctzll(bm); bm &= bm - 1;
            float v = __shfl(a[j], src);
            int n = src * 4 + (j & 3) + ((j >= 4) ? 256 : 0);
            float4 w = *(const float4*)(wp + (size_t)n * 256 + lane * 4);
            acc4.x = fmaf(v, w.x, acc4.x);
            acc4.y = fmaf(v, w.y, acc4.y);
            acc4.z = fmaf(v, w.z, acc4.z);
            acc4.w = fmaf(v, w.w, acc4.w);
        }
    }
    size_t ob = (size_t)row * 256 + lane * 4;
    float4 xv = *(const float4*)(x_in + (size_t)b * 256 + lane * 4);
    *(float4*)(pred + ob) = acc4;
    float4 e = {xv.x - acc4.x, xv.y - acc4.y, xv.z - acc4.z, xv.w - acc4.w};
    *(float4*)(err + ob) = e;
}

// ---------------------------------------------------------------------------
extern "C" void kernel_launch(void* const* d_in, const int* in_sizes, int n_in,
                              void* d_out, int out_size, void* d_ws, size_t ws_size,
                              hipStream_t stream)
{
    const float* x_in   = (const float*)d_in[0];
    const float* x_ctx  = (const float*)d_in[1];
    const float* W_ff   = (const float*)d_in[2];
    const float* W_ctx  = (const float*)d_in[3];
    const float* W_pred = (const float*)d_in[4];
    const float* bias   = (const float*)d_in[5];
    const float* avg    = (const float*)d_in[6];
    const int*   kptr   = (const int*)d_in[7];

    float* act  = (float*)d_out;                        // [B,C,N]
    float* pred = act  + (size_t)B_ * C_ * N_;          // [B,C,D]
    float* err  = pred + (size_t)B_ * C_ * D_;          // [B,C,D]

    const size_t WS_NEED = ((size_t)66 << 20) + (size_t)32768 * 4;
    if (ws_size >= WS_NEED) {
        char* ws = (char*)d_ws;
        short* Ahi = (short*)(ws);
        short* Alo = (short*)(ws + ((size_t)1 << 20));
        short* Whi = (short*)(ws + ((size_t)2 << 20));
        short* Wlo = (short*)(ws + ((size_t)2 << 20) + ((size_t)32 << 20));
        float* boost = (float*)(ws + ((size_t)66 << 20));

        k_split_x<<<256, 256, 0, stream>>>(x_in, x_ctx, Ahi, Alo);
        k_split_w<<<8192, 256, 0, stream>>>(W_ff, W_ctx, Whi, Wlo);
        k_boost<<<128, 256, 0, stream>>>(avg, boost);
        dim3 g(4, 8, 64);
        k_drive_mfma<<<g, 256, 0, stream>>>(Ahi, Alo, Whi, Wlo, bias, act);
        k_select<<<(B_ * C_) / 4, 256, 0, stream>>>(x_in, x_ctx, W_ff, W_ctx, W_pred,
                                                    bias, avg, boost, kptr,
                                                    act, pred, err);
    } else {
        dim3 g1(4, 8, 64);
        k_drive<<<g1, 256, 0, stream>>>(x_in, x_ctx, W_ff, W_ctx, bias, act);
        k_select<<<(B_ * C_) / 4, 256, 0, stream>>>(x_in, x_ctx, W_ff, W_ctx, W_pred,
                                                    bias, avg, (const float*)nullptr,
                                                    kptr, act, pred, err);
    }
}

// Round 3
// 774.952 us; speedup vs baseline: 1.5406x; 1.0974x over previous
//
#include <hip/hip_runtime.h>
#include <math.h>

#define B_ 1024
#define C_ 64
#define D_ 256
#define N_ 512

#define TOPK_MARGIN 4e-4f

typedef __attribute__((ext_vector_type(8))) short short8;
typedef __attribute__((ext_vector_type(4))) float f32x4;

// ---------------------------------------------------------------------------
// helpers
// ---------------------------------------------------------------------------
__device__ __forceinline__ float wredmaxf(float v) {
#pragma unroll
    for (int o = 32; o; o >>= 1) v = fmaxf(v, __shfl_xor(v, o));
    return v;
}
__device__ __forceinline__ float wredsumf(float v) {
#pragma unroll
    for (int o = 32; o; o >>= 1) v += __shfl_xor(v, o);
    return v;
}
__device__ __forceinline__ int wredsumi(int v) {
#pragma unroll
    for (int o = 32; o; o >>= 1) v += __shfl_xor(v, o);
    return v;
}
__device__ __forceinline__ double wredsumd(double v) {
#pragma unroll
    for (int o = 32; o; o >>= 1) v += __shfl_xor(v, o);
    return v;
}
__device__ __forceinline__ double wredmaxd(double v) {
#pragma unroll
    for (int o = 32; o; o >>= 1) { double t = __shfl_xor(v, o); v = (t > v) ? t : v; }
    return v;
}

// split f32 -> bf16 hi + bf16 lo (truncation; residual ~2^-17 relative)
__device__ __forceinline__ void split8(const float* v, short8* hi, short8* lo) {
    short8 h, l;
#pragma unroll
    for (int q = 0; q < 8; ++q) {
        unsigned u = __float_as_uint(v[q]);
        float hf = __uint_as_float(u & 0xFFFF0000u);
        float lf = v[q] - hf;
        h[q] = (short)(u >> 16);
        l[q] = (short)(__float_as_uint(lf) >> 16);
    }
    *hi = h; *lo = l;
}

__device__ __forceinline__ void gload_lds16(const void* g, void* l) {
    __builtin_amdgcn_global_load_lds(
        (const __attribute__((address_space(1))) void*)g,
        (__attribute__((address_space(3))) void*)l, 16, 0, 0);
}

// ---------------------------------------------------------------------------
// P1: split X = [x_in | 0.3*x_ctx]  (B x 512 f32) into bf16 hi/lo,
// layout Ahi[kb][b][k'] (kb = k/64, k' = k%64), k-contiguous.
// ---------------------------------------------------------------------------
__global__ __launch_bounds__(256)
void k_split_x(const float* __restrict__ x_in, const float* __restrict__ x_ctx,
               short* __restrict__ Ahi, short* __restrict__ Alo)
{
    int gid = blockIdx.x * 256 + threadIdx.x;       // 65536 = 1024 rows * 64
    int b = gid >> 6, tn = gid & 63, k0 = tn * 8;
    float v[8];
    if (k0 < 256) {
        *(float4*)&v[0] = *(const float4*)(x_in + (size_t)b * 256 + k0);
        *(float4*)&v[4] = *(const float4*)(x_in + (size_t)b * 256 + k0 + 4);
    } else {
        *(float4*)&v[0] = *(const float4*)(x_ctx + (size_t)b * 256 + k0 - 256);
        *(float4*)&v[4] = *(const float4*)(x_ctx + (size_t)b * 256 + k0 - 252);
#pragma unroll
        for (int q = 0; q < 8; ++q) v[q] *= 0.3f;
    }
    short8 h, l; split8(v, &h, &l);
    size_t off = ((size_t)(k0 >> 6) * 1024 + b) * 64 + (k0 & 63);
    *(short8*)(Ahi + off) = h;
    *(short8*)(Alo + off) = l;
}

// ---------------------------------------------------------------------------
// P2: split Wcat[c][k][n] (k<256 -> W_ff, else W_ctx) into bf16 hi/lo,
// layout Whi[c][nb(4)][kb(8)][n'(128)][k'(64)]  (16KB tiles, k-contiguous).
// ---------------------------------------------------------------------------
__global__ __launch_bounds__(256)
void k_split_w(const float* __restrict__ W_ff, const float* __restrict__ W_ctx,
               short* __restrict__ Whi, short* __restrict__ Wlo)
{
    int blk = blockIdx.x;                            // 8192 = 64c * 128
    int c = blk >> 7;
    int t = (blk & 127) * 256 + threadIdx.x;         // 0..32767 = 64kg * 512n
    int kg = t >> 9, n = t & 511, k0 = kg * 8;
    const float* src = (k0 < 256)
        ? (W_ff  + ((size_t)c * 256 + k0) * 512 + n)
        : (W_ctx + ((size_t)c * 256 + (k0 - 256)) * 512 + n);
    float v[8];
#pragma unroll
    for (int q = 0; q < 8; ++q) v[q] = src[(size_t)q * 512];
    short8 h, l; split8(v, &h, &l);
    size_t off = ((((size_t)c * 4 + (n >> 7)) * 8 + (k0 >> 6)) * 128 + (n & 127)) * 64
               + (k0 & 63);
    *(short8*)(Whi + off) = h;
    *(short8*)(Wlo + off) = l;
}

// ---------------------------------------------------------------------------
// P3: boost table  boost[c][n] = log1pf(0.05/(avg+1e-6))
// ---------------------------------------------------------------------------
__global__ __launch_bounds__(256)
void k_boost(const float* __restrict__ avg, float* __restrict__ boost)
{
    int i = blockIdx.x * 256 + threadIdx.x;          // 32768
    boost[i] = log1pf(0.05f / (avg[i] + 1e-6f));
}

// ---------------------------------------------------------------------------
// G: drive GEMM via MFMA 16x16x32 bf16, 3-product split.
// 128x128 tile, BK=64, 4 waves (2x2, each 64x64), 2-barrier loop,
// global_load_lds width 16 (linear LDS dest) + inverse-swizzled global src,
// XOR-swizzled ds_read (T2 both-sides, rule #21).
// 1D grid, mb innermost + bijective XCD chunking: the 8 mb-blocks sharing a
// (c,nb) W-slab co-reside on one XCD -> W fetched ~once from HBM.
// ---------------------------------------------------------------------------
__global__ __launch_bounds__(256)
void k_drive_mfma(const short* __restrict__ Ahi, const short* __restrict__ Alo,
                  const short* __restrict__ Whi, const short* __restrict__ Wlo,
                  const float* __restrict__ bias, float* __restrict__ drive)
{
    __shared__ short lds[32768];                     // 4 x 16KB tiles
    // XCD-chunked decode: 2048 blocks, 256 per XCD chunk
    const int w  = (blockIdx.x & 7) * 256 + (blockIdx.x >> 3);
    const int mb = w & 7, nb = (w >> 3) & 3, c = w >> 5;
    const int tid = threadIdx.x, lane = tid & 63, wid = tid >> 6;
    const int wm = wid >> 1, wn = wid & 1;
    const int m0 = mb * 128, n0 = nb * 128;

    f32x4 acc[4][4];
#pragma unroll
    for (int i = 0; i < 4; ++i)
#pragma unroll
        for (int j = 0; j < 4; ++j) acc[i][j] = (f32x4){0.f, 0.f, 0.f, 0.f};

    // per-wave staging assignment: wave w stages tile w
    const short* gbase;
    size_t kstep;
    if (wid == 0)      { gbase = Ahi + (size_t)m0 * 64;                   kstep = 65536; }
    else if (wid == 1) { gbase = Alo + (size_t)m0 * 64;                   kstep = 65536; }
    else if (wid == 2) { gbase = Whi + ((size_t)(c * 4 + nb) * 8) * 8192; kstep = 8192; }
    else               { gbase = Wlo + ((size_t)(c * 4 + nb) * 8) * 8192; kstep = 8192; }
    short* lbase = lds + wid * 8192;
    // inverse-swizzle the per-lane global source chunk (m173 pattern):
    // LDS(row,chunk) must hold G(row, chunk ^ (row&7)); staging row = i*8+(lane>>3)
    const int swzoff = ((lane & 56) | ((lane & 7) ^ ((lane >> 3) & 7))) * 8;

    for (int kb = 0; kb < 8; ++kb) {
        const short* g = gbase + (size_t)kb * kstep + swzoff;
#pragma unroll
        for (int i = 0; i < 16; ++i)
            gload_lds16(g + i * 512, lbase + i * 512);
        __syncthreads();                 // compiler drains vmcnt before barrier

        const int rA = lane & 15;
#pragma unroll
        for (int s = 0; s < 2; ++s) {
            const int ko = s * 32 + (lane >> 4) * 8;
            const int chk = ko >> 3;
            short8 ah[4], al[4], bh[4], bl[4];
#pragma unroll
            for (int i = 0; i < 4; ++i) {
                int rowA = wm * 64 + i * 16 + rA;
                int offA = rowA * 64 + ((chk ^ (rowA & 7)) << 3);
                ah[i] = *(const short8*)(lds + offA);
                al[i] = *(const short8*)(lds + 8192 + offA);
                int rowB = wn * 64 + i * 16 + rA;
                int offB = rowB * 64 + ((chk ^ (rowB & 7)) << 3);
                bh[i] = *(const short8*)(lds + 16384 + offB);
                bl[i] = *(const short8*)(lds + 24576 + offB);
            }
#pragma unroll
            for (int i = 0; i < 4; ++i)
#pragma unroll
                for (int j = 0; j < 4; ++j) {
                    acc[i][j] = __builtin_amdgcn_mfma_f32_16x16x32_bf16(ah[i], bh[j], acc[i][j], 0, 0, 0);
                    acc[i][j] = __builtin_amdgcn_mfma_f32_16x16x32_bf16(ah[i], bl[j], acc[i][j], 0, 0, 0);
                    acc[i][j] = __builtin_amdgcn_mfma_f32_16x16x32_bf16(al[i], bh[j], acc[i][j], 0, 0, 0);
                }
        }
        __syncthreads();
    }

    // epilogue: + bias, store. C/D layout: col=lane&15, row=(lane>>4)*4+reg
    const int col = lane & 15, rq = (lane >> 4) * 4;
#pragma unroll
    for (int j = 0; j < 4; ++j) {
        float bv = bias[(size_t)c * 512 + n0 + wn * 64 + j * 16 + col];
#pragma unroll
        for (int i = 0; i < 4; ++i) {
#pragma unroll
            for (int r = 0; r < 4; ++r) {
                int bi = m0 + wm * 64 + i * 16 + rq + r;
                drive[((size_t)bi * 64 + c) * 512 + n0 + wn * 64 + j * 16 + col]
                    = acc[i][j][r] + bv;
            }
        }
    }
}

// ---------------------------------------------------------------------------
// Fallback f32 drive GEMM (used only if ws too small)
// ---------------------------------------------------------------------------
__global__ __launch_bounds__(256)
void k_drive(const float* __restrict__ x_in, const float* __restrict__ x_ctx,
             const float* __restrict__ W_ff, const float* __restrict__ W_ctx,
             const float* __restrict__ bias, float* __restrict__ drive)
{
    __shared__ float Xs[32][132];
    __shared__ float Ws[32][132];
    const int c  = blockIdx.z;
    const int m0 = blockIdx.y * 128;
    const int n0 = blockIdx.x * 128;
    const int tid = threadIdx.x;
    const int tx = tid & 15;
    const int ty = tid >> 4;

    float acc[8][8];
#pragma unroll
    for (int i = 0; i < 8; ++i)
#pragma unroll
        for (int j = 0; j < 8; ++j) acc[i][j] = 0.f;

    const size_t wbase = (size_t)c * D_ * N_;

    for (int kb = 0; kb < 512; kb += 32) {
#pragma unroll
        for (int i = 0; i < 4; ++i) {
            int idx = tid + i * 256;
            int row = idx >> 3;
            int kf4 = idx & 7;
            float4 v;
            if (kb < 256) {
                v = *(const float4*)(x_in + (size_t)(m0 + row) * D_ + kb + kf4 * 4);
            } else {
                v = *(const float4*)(x_ctx + (size_t)(m0 + row) * D_ + (kb - 256) + kf4 * 4);
                v.x *= 0.3f; v.y *= 0.3f; v.z *= 0.3f; v.w *= 0.3f;
            }
            Xs[kf4 * 4 + 0][row] = v.x;
            Xs[kf4 * 4 + 1][row] = v.y;
            Xs[kf4 * 4 + 2][row] = v.z;
            Xs[kf4 * 4 + 3][row] = v.w;
        }
#pragma unroll
        for (int i = 0; i < 4; ++i) {
            int idx = tid + i * 256;
            int kk  = idx >> 5;
            int nf4 = idx & 31;
            const float* src = (kb < 256)
                ? (W_ff  + wbase + (size_t)(kb + kk) * N_ + n0 + nf4 * 4)
                : (W_ctx + wbase + (size_t)(kb - 256 + kk) * N_ + n0 + nf4 * 4);
            *(float4*)&Ws[kk][nf4 * 4] = *(const float4*)src;
        }
        __syncthreads();
#pragma unroll
        for (int kk = 0; kk < 32; ++kk) {
            float xr[8], wr[8];
            *(float4*)&xr[0] = *(const float4*)&Xs[kk][ty * 8];
            *(float4*)&xr[4] = *(const float4*)&Xs[kk][ty * 8 + 4];
            *(float4*)&wr[0] = *(const float4*)&Ws[kk][tx * 8];
            *(float4*)&wr[4] = *(const float4*)&Ws[kk][tx * 8 + 4];
#pragma unroll
            for (int i = 0; i < 8; ++i)
#pragma unroll
                for (int j = 0; j < 8; ++j)
                    acc[i][j] = fmaf(xr[i], wr[j], acc[i][j]);
        }
        __syncthreads();
    }
    float bv[8];
    *(float4*)&bv[0] = *(const float4*)(bias + (size_t)c * N_ + n0 + tx * 8);
    *(float4*)&bv[4] = *(const float4*)(bias + (size_t)c * N_ + n0 + tx * 8 + 4);
#pragma unroll
    for (int i = 0; i < 8; ++i) {
        int b = m0 + ty * 8 + i;
        float o[8];
#pragma unroll
        for (int j = 0; j < 8; ++j) o[j] = acc[i][j] + bv[j];
        float* dst = drive + ((size_t)b * C_ + c) * N_ + n0 + tx * 8;
        *(float4*)dst       = *(float4*)&o[0];
        *(float4*)(dst + 4) = *(float4*)&o[4];
    }
}

// ---------------------------------------------------------------------------
// k_select: fused top-k mask + normalize + predictions + errors.
// One wave per (b,c) row; element j of lane L is n = L*4 + (j&3) + (j>=4)*256.
// c-major grid + XCD chunking: concurrent blocks share 1-2 c values ->
// W_pred slab (512KB/c) and band-fixup W slabs stay L2-resident.
// ---------------------------------------------------------------------------
__global__ __launch_bounds__(256)
void k_select(const float* __restrict__ x_in, const float* __restrict__ x_ctx,
              const float* __restrict__ W_ff, const float* __restrict__ W_ctx,
              const float* __restrict__ W_pred,
              const float* __restrict__ bias, const float* __restrict__ avg_act,
              const float* __restrict__ boost_tab,
              const int* __restrict__ kptr,
              float* __restrict__ act, float* __restrict__ pred,
              float* __restrict__ err)
{
    const int wave = threadIdx.x >> 6, lane = threadIdx.x & 63;
    // XCD-chunked, c-major decode: 16384 blocks, 2048 per XCD chunk
    const int wrk = (blockIdx.x & 7) * 2048 + (blockIdx.x >> 3);
    const int c = wrk >> 8;                         // 256 blocks per c
    const int b = (wrk & 255) * 4 + wave;
    const int row = b * 64 + c;
    const int kv = *kptr;

    float* arow = act + (size_t)row * N_;
    const float* avgrow = avg_act + (size_t)c * N_;

    float drv[8], boo[8];
    {
        float4 d0 = *(const float4*)(arow + lane * 4);
        float4 d1 = *(const float4*)(arow + 256 + lane * 4);
        drv[0] = d0.x; drv[1] = d0.y; drv[2] = d0.z; drv[3] = d0.w;
        drv[4] = d1.x; drv[5] = d1.y; drv[6] = d1.z; drv[7] = d1.w;
    }
    if (boost_tab) {
        float4 t0 = *(const float4*)(boost_tab + (size_t)c * 512 + lane * 4);
        float4 t1 = *(const float4*)(boost_tab + (size_t)c * 512 + 256 + lane * 4);
        boo[0] = drv[0] + t0.x; boo[1] = drv[1] + t0.y;
        boo[2] = drv[2] + t0.z; boo[3] = drv[3] + t0.w;
        boo[4] = drv[4] + t1.x; boo[5] = drv[5] + t1.y;
        boo[6] = drv[6] + t1.z; boo[7] = drv[7] + t1.w;
    } else {
#pragma unroll
        for (int j = 0; j < 8; ++j) {
            int n = lane * 4 + (j & 3) + ((j >= 4) ? 256 : 0);
            boo[j] = drv[j] + log1pf(0.05f / (avgrow[n] + 1e-6f));
        }
    }

    // ---- exact top-kv threshold by iterative extraction (f32) ----
    unsigned exm = 0;
    float t = 0.f;
    for (int it = 0; it < kv; ++it) {
        float lm = -INFINITY; int li = -1;
#pragma unroll
        for (int j = 0; j < 8; ++j)
            if (!((exm >> j) & 1u) && boo[j] > lm) { lm = boo[j]; li = j; }
        float wm = wredmaxf(lm);
        unsigned long long bal = __ballot(lm == wm);
        int lowest = (int)__builtin_ctzll(bal);
        if (lane == lowest) exm |= (1u << li);
        t = wm;
    }

    // ---- band analysis ----
    bool inband[8], sel[8];
    int cb_l = 0, cs_l = 0;
#pragma unroll
    for (int j = 0; j < 8; ++j) {
        inband[j] = fabsf(boo[j] - t) <= TOPK_MARGIN;
        cb_l += inband[j] ? 1 : 0;
        cs_l += (boo[j] > t + TOPK_MARGIN) ? 1 : 0;
        sel[j] = (boo[j] >= t);
    }
    int cb = wredsumi(cb_l);
    int cs = wredsumi(cs_l);

    if (cb > 1) {
        // ---- f64 fixup, band elements distributed one per lane ----
        int nbTot = 0;
        double myv = -1e300; int myn = -1;
        const float* xi = x_in + (size_t)b * 256;
        const float* xc = x_ctx + (size_t)b * 256;
        const size_t wb = (size_t)c * 256 * 512;
        const float* brow = bias + (size_t)c * 512;
        for (int j = 0; j < 8; ++j) {
            unsigned long long bm = __ballot(inband[j]);
            while (bm && nbTot < 64) {
                int L = (int)__builtin_ctzll(bm); bm &= bm - 1;
                int n = L * 4 + (j & 3) + ((j >= 4) ? 256 : 0);
                double sff = 0.0, sct = 0.0;
#pragma unroll
                for (int dd = 0; dd < 4; ++dd) {
                    int d = lane + (dd << 6);
                    sff += (double)xi[d] * (double)W_ff[wb + (size_t)d * 512 + n];
                    sct += (double)xc[d] * (double)W_ctx[wb + (size_t)d * 512 + n];
                }
                sff = wredsumd(sff);
                sct = wredsumd(sct);
                double b64 = sff + sct * 0.3 + (double)brow[n]
                           + log1p(0.05 / ((double)avgrow[n] + 1e-6));
                if (lane == nbTot) { myv = b64; myn = n; }
                ++nbTot;
            }
        }
        int need = kv - cs;
        if (need < 1) need = 1;
        if (need > nbTot) need = nbTot;
        double cur = myv, thr = 0.0;
        for (int it = 0; it < need; ++it) {
            double m = wredmaxd(cur);
            unsigned long long balm = __ballot(cur == m);
            int low = (int)__builtin_ctzll(balm);
            if (lane == low) cur = -1e300;
            thr = m;
        }
        int mysel = (myn >= 0 && myv >= thr) ? 1 : 0;
        for (int q = 0; q < nbTot; ++q) {
            int nq = __shfl(myn, q);
            int sq = __shfl(mysel, q);
            int tl = (nq & 255) >> 2;
            int tj = (nq & 3) + ((nq >= 256) ? 4 : 0);
            if (lane == tl) sel[tj] = (sq != 0);
        }
    }

    // ---- relu * mask, normalize to sum k, store act ----
    float a[8]; float s_l = 0.f;
#pragma unroll
    for (int j = 0; j < 8; ++j) {
        a[j] = sel[j] ? fmaxf(drv[j], 0.f) : 0.f;
        s_l += a[j];
    }
    float s = wredsumf(s_l);
    float scale = (float)kv / (s + 1e-8f);
#pragma unroll
    for (int j = 0; j < 8; ++j) a[j] *= scale;
    {
        float4 o0 = {a[0], a[1], a[2], a[3]};
        float4 o1 = {a[4], a[5], a[6], a[7]};
        *(float4*)(arow + lane * 4) = o0;
        *(float4*)(arow + 256 + lane * 4) = o1;
    }

    // ---- predictions + errors (fused; winners broadcast via ballot) ----
    float4 acc4 = {0.f, 0.f, 0.f, 0.f};
    const float* wp = W_pred + (size_t)c * (N_ * D_);
    for (int j = 0; j < 8; ++j) {
        unsigned long long bm = __ballot(a[j] != 0.f);
        while (bm) {
            int src = (int)__builtin_ctzll(bm); bm &= bm - 1;
            float v = __shfl(a[j], src);
            int n = src * 4 + (j & 3) + ((j >= 4) ? 256 : 0);
            float4 w = *(const float4*)(wp + (size_t)n * 256 + lane * 4);
            acc4.x = fmaf(v, w.x, acc4.x);
            acc4.y = fmaf(v, w.y, acc4.y);
            acc4.z = fmaf(v, w.z, acc4.z);
            acc4.w = fmaf(v, w.w, acc4.w);
        }
    }
    size_t ob = (size_t)row * 256 + lane * 4;
    float4 xv = *(const float4*)(x_in + (size_t)b * 256 + lane * 4);
    *(float4*)(pred + ob) = acc4;
    float4 e = {xv.x - acc4.x, xv.y - acc4.y, xv.z - acc4.z, xv.w - acc4.w};
    *(float4*)(err + ob) = e;
}

// ---------------------------------------------------------------------------
extern "C" void kernel_launch(void* const* d_in, const int* in_sizes, int n_in,
                              void* d_out, int out_size, void* d_ws, size_t ws_size,
                              hipStream_t stream)
{
    const float* x_in   = (const float*)d_in[0];
    const float* x_ctx  = (const float*)d_in[1];
    const float* W_ff   = (const float*)d_in[2];
    const float* W_ctx  = (const float*)d_in[3];
    const float* W_pred = (const float*)d_in[4];
    const float* bias   = (const float*)d_in[5];
    const float* avg    = (const float*)d_in[6];
    const int*   kptr   = (const int*)d_in[7];

    float* act  = (float*)d_out;                        // [B,C,N]
    float* pred = act  + (size_t)B_ * C_ * N_;          // [B,C,D]
    float* err  = pred + (size_t)B_ * C_ * D_;          // [B,C,D]

    const size_t WS_NEED = ((size_t)66 << 20) + (size_t)32768 * 4;
    if (ws_size >= WS_NEED) {
        char* ws = (char*)d_ws;
        short* Ahi = (short*)(ws);
        short* Alo = (short*)(ws + ((size_t)1 << 20));
        short* Whi = (short*)(ws + ((size_t)2 << 20));
        short* Wlo = (short*)(ws + ((size_t)2 << 20) + ((size_t)32 << 20));
        float* boost = (float*)(ws + ((size_t)66 << 20));

        k_split_x<<<256, 256, 0, stream>>>(x_in, x_ctx, Ahi, Alo);
        k_split_w<<<8192, 256, 0, stream>>>(W_ff, W_ctx, Whi, Wlo);
        k_boost<<<128, 256, 0, stream>>>(avg, boost);
        k_drive_mfma<<<2048, 256, 0, stream>>>(Ahi, Alo, Whi, Wlo, bias, act);
        k_select<<<(B_ * C_) / 4, 256, 0, stream>>>(x_in, x_ctx, W_ff, W_ctx, W_pred,
                                                    bias, avg, boost, kptr,
                                                    act, pred, err);
    } else {
        dim3 g1(4, 8, 64);
        k_drive<<<g1, 256, 0, stream>>>(x_in, x_ctx, W_ff, W_ctx, bias, act);
        k_select<<<(B_ * C_) / 4, 256, 0, stream>>>(x_in, x_ctx, W_ff, W_ctx, W_pred,
                                                    bias, avg, (const float*)nullptr,
                                                    kptr, act, pred, err);
    }
}